// Round 2
// baseline (125.023 us; speedup 1.0000x reference)
//
#include <hip/hip_runtime.h>

// Depthwise Gaussian blur, K=121, replicate pad -> SEPARABLE: two 1D passes.
// x: (8,3,512,512) fp32, sigma scalar fp32. out fp32 same shape.
// R2: weights computed in-kernel into LDS (no gauss_weights dispatch, no
// global weight loads in the hot loop); blur_h rebuilt as ping-pong sliding
// window mirroring blur_v.

#define HH   512
#define WW   512
#define NIMG 24          // 8*3 independent planes
#define RAD  60

// Every thread computes the full normalization sum itself (121 __expf,
// ~500 cyc, no barriers); threads 0..127 write the normalized 1D kernel
// (zero-padded to 128 taps) into LDS. Caller's later __syncthreads covers it.
__device__ __forceinline__ void make_weights(const float* __restrict__ sigma,
                                             float* __restrict__ wlds, int tid) {
    const float s = sigma[0] * 8.0f + 16.0f;
    const float inv2v = 1.0f / (2.0f * s * s);
    float sum = 0.0f;
    #pragma unroll
    for (int k = 0; k <= 120; ++k) {
        const float c = (float)k - 60.0f;
        sum += __expf(-c * c * inv2v);
    }
    if (tid < 128) {
        float g = 0.0f;
        if (tid < 121) {
            const float c = (float)tid - 60.0f;
            g = __expf(-c * c * inv2v);
        }
        wlds[tid] = g / sum;   // taps 121..127 are exactly 0
    }
}

// ---------------- vertical pass ---------------------------------------------
// Tile: 256 output rows x 32 cols. LDS holds 384 input rows x 32 cols (48 KB).
// Thread = (tx 0..7: float4 col group) x (tid>>3: 8 consecutive output rows).
// 8-row ping-pong register window; weights via LDS broadcast reads.

#define V_OCT(CUR, NXT, KO)                                               \
    { *(float4*)&wq[0] = *(const float4*)&wlds[(KO) * 8];                 \
      *(float4*)&wq[4] = *(const float4*)&wlds[(KO) * 8 + 4];             \
      _Pragma("unroll")                                                   \
      for (int ki = 0; ki < 8; ++ki) {                                    \
          NXT[ki] = sm4[(r0 + ((KO) + 1) * 8 + ki) * 8 + tx];             \
          const float wk = wq[ki];                                        \
          _Pragma("unroll")                                               \
          for (int j = 0; j < 8; ++j) {                                   \
              const int idx = ki + j;                                     \
              const float4 v = (idx < 8) ? CUR[idx] : NXT[idx - 8];       \
              acc[j].x += wk * v.x; acc[j].y += wk * v.y;                 \
              acc[j].z += wk * v.z; acc[j].w += wk * v.w;                 \
          }                                                               \
      }                                                                   \
    }

__global__ __launch_bounds__(256, 3) void blur_v(
        const float* __restrict__ x, const float* __restrict__ sigma,
        float* __restrict__ tmp) {
    __shared__ float sm[384 * 32];                   // 48 KB -> 3 blocks/CU
    __shared__ float wlds[128];
    const int tid = threadIdx.x;
    const int w0  = blockIdx.x * 32;
    const int h0  = blockIdx.y * 256;
    const float* __restrict__ src = x + (size_t)blockIdx.z * (HH * WW);

    // stage 384 rows x 32 cols (row-clamped), coalesced 128B per octet
    {
        const int fc = (tid & 7) * 4;
        int r = tid >> 3;
        #pragma unroll
        for (int it = 0; it < 12; ++it, r += 32) {
            int gr = h0 - RAD + r;
            gr = gr < 0 ? 0 : (gr > HH - 1 ? HH - 1 : gr);
            *(float4*)&sm[r * 32 + fc] =
                *(const float4*)&src[(size_t)gr * WW + w0 + fc];
        }
    }
    make_weights(sigma, wlds, tid);
    __syncthreads();

    const int tx = tid & 7;
    const int r0 = (tid >> 3) * 8;                   // first output row (local)
    const float4* __restrict__ sm4 = (const float4*)sm;   // row = 8 float4

    float4 acc[8];
    #pragma unroll
    for (int j = 0; j < 8; ++j) acc[j] = make_float4(0.f, 0.f, 0.f, 0.f);

    float4 wa[8], wb[8];
    float  wq[8];
    #pragma unroll
    for (int m = 0; m < 8; ++m) wa[m] = sm4[(r0 + m) * 8 + tx];

    #pragma unroll 1
    for (int ko = 0; ko < 16; ko += 2) {             // 128 taps, ping-pong
        V_OCT(wa, wb, ko)
        V_OCT(wb, wa, ko + 1)
    }

    float* __restrict__ dst = tmp + (size_t)blockIdx.z * (HH * WW);
    #pragma unroll
    for (int j = 0; j < 8; ++j)
        *(float4*)&dst[(size_t)(h0 + r0 + j) * WW + w0 + tx * 4] = acc[j];
}

// ---------------- horizontal pass -------------------------------------------
// Tile: 4 rows x full 512-wide row. 640 halo cols per row in LDS as 80 groups
// of (8 floats + 4 pad) = 12-float stride -> lane f4-stride 3 (odd), 2
// accesses/bank/phase = conflict-free. Lane computes 8 consecutive cols with
// a 16-float ping-pong window; weights via LDS broadcast.
#define HP_ROW 960   // 80 groups * 12 floats

#define H_OCT(CUR, NXT, KO)                                               \
    { const int gbase = (lane + (KO) + 1) * 12;                           \
      *(float4*)&NXT[0] = *(const float4*)&bs[gbase];                     \
      *(float4*)&NXT[4] = *(const float4*)&bs[gbase + 4];                 \
      *(float4*)&wq[0] = *(const float4*)&wlds[(KO) * 8];                 \
      *(float4*)&wq[4] = *(const float4*)&wlds[(KO) * 8 + 4];             \
      _Pragma("unroll")                                                   \
      for (int ki = 0; ki < 8; ++ki) {                                    \
          const float wk = wq[ki];                                        \
          _Pragma("unroll")                                               \
          for (int j = 0; j < 8; ++j) {                                   \
              const int idx = ki + j;                                     \
              const float v = (idx < 8) ? CUR[idx] : NXT[idx - 8];        \
              acc[j] += wk * v;                                           \
          }                                                               \
      }                                                                   \
    }

__global__ __launch_bounds__(256, 4) void blur_h(
        const float* __restrict__ tmp, const float* __restrict__ sigma,
        float* __restrict__ out) {
    __shared__ float sm[4 * HP_ROW];                 // 15 KB
    __shared__ float wlds[128];
    const int tid = threadIdx.x;
    const int h0  = blockIdx.x * 4;
    const float* __restrict__ src = tmp + (size_t)blockIdx.y * (HH * WW);

    #pragma unroll
    for (int it = 0; it < 3; ++it) {                 // 640 cols staged
        const int c = tid + it * 256;
        if (c < 640) {
            int gc = c - RAD;
            gc = gc < 0 ? 0 : (gc > WW - 1 ? WW - 1 : gc);
            const int la = ((c >> 3) * 12) + (c & 7);
            #pragma unroll
            for (int r = 0; r < 4; ++r)
                sm[r * HP_ROW + la] = src[(size_t)(h0 + r) * WW + gc];
        }
    }
    make_weights(sigma, wlds, tid);
    __syncthreads();

    const int row  = tid >> 6;                       // 0..3 (wave-uniform)
    const int lane = tid & 63;                       // output cols lane*8..+7
    const float* __restrict__ bs = sm + row * HP_ROW;

    float a[8], b[8], wq[8];
    float acc[8];
    #pragma unroll
    for (int j = 0; j < 8; ++j) acc[j] = 0.0f;

    *(float4*)&a[0] = *(const float4*)&bs[lane * 12];
    *(float4*)&a[4] = *(const float4*)&bs[lane * 12 + 4];

    #pragma unroll 1
    for (int ko = 0; ko < 16; ko += 2) {             // 128 taps, ping-pong
        H_OCT(a, b, ko)
        H_OCT(b, a, ko + 1)
    }

    float* __restrict__ dst = out + (size_t)blockIdx.y * (HH * WW)
                                  + (size_t)(h0 + row) * WW + lane * 8;
    *(float4*)dst       = make_float4(acc[0], acc[1], acc[2], acc[3]);
    *(float4*)(dst + 4) = make_float4(acc[4], acc[5], acc[6], acc[7]);
}

// ---------------- launch -----------------------------------------------------
extern "C" void kernel_launch(void* const* d_in, const int* in_sizes, int n_in,
                              void* d_out, int out_size, void* d_ws, size_t ws_size,
                              hipStream_t stream) {
    const float* x     = (const float*)d_in[0];
    const float* sigma = (const float*)d_in[1];
    float* out = (float*)d_out;
    float* tmp = (float*)d_ws;                       // 24*512*512 floats (~25.2 MB)

    blur_v<<<dim3(WW / 32, HH / 256, NIMG), dim3(256), 0, stream>>>(x, sigma, tmp);
    blur_h<<<dim3(HH / 4, NIMG), dim3(256), 0, stream>>>(tmp, sigma, out);
}